// Round 11
// baseline (272.131 us; speedup 1.0000x reference)
//
#include <hip/hip_runtime.h>
#include <stdint.h>

typedef unsigned short u16;
typedef __attribute__((ext_vector_type(8))) __bf16 bf16x8;
typedef __attribute__((ext_vector_type(4))) __bf16 bf16x4;
typedef __attribute__((ext_vector_type(8))) unsigned short u16x8;
typedef __attribute__((ext_vector_type(4))) float f32x4;

// async global->LDS, 16B/lane; LDS dest = wave-uniform base + lane*16.
__device__ __forceinline__ void glds16(const u16* g, u16* l) {
  auto* gp = reinterpret_cast<const __attribute__((address_space(1))) unsigned*>(
      reinterpret_cast<uintptr_t>(g));
  auto* lp = reinterpret_cast<__attribute__((address_space(3))) unsigned*>(
      reinterpret_cast<uintptr_t>(l));
  __builtin_amdgcn_global_load_lds(gp, lp, 16, 0, 0);
}

// drain own vmem, then raw barrier. lgkmcnt wait is NOT needed here:
// P is wave-private, and K/V LDS reads are data-consumed (compiler-inserted
// lgkm waits before the MFMAs) before any wave reaches the barrier; the only
// cross-wave hazard is glds arrival = vmcnt.
__device__ __forceinline__ void pipe_bar() {
  asm volatile("s_waitcnt vmcnt(0)" ::: "memory");
  __builtin_amdgcn_s_barrier();
  asm volatile("" ::: "memory");
}

// ---------------- prep: weight transposes + x cvt (fp32 -> bf16) ----------
// scale folded in BEFORE the bf16 round (pre-scales Q by log2e/8).
__device__ __forceinline__ void tp_tile(const float* __restrict__ src,
                                        u16* __restrict__ dst, int C, int Rd,
                                        int r0, int c0, float scale, u16* lds) {
  const int tid = threadIdx.x;
  {
    int r = tid >> 2, cb = (tid & 3) * 16;
#pragma unroll
    for (int k = 0; k < 4; ++k) {
      f32x4 v = *(const f32x4*)&src[(long)(r0 + r) * C + c0 + cb + k * 4];
      v = v * scale;
      *(bf16x4*)&lds[r * 72 + cb + k * 4] = __builtin_convertvector(v, bf16x4);
    }
  }
  __syncthreads();
  {
    int c = tid >> 2, rb = (tid & 3) * 16;
    u16x8 o0, o1;
#pragma unroll
    for (int q = 0; q < 8; ++q) {
      o0[q] = lds[(rb + q) * 72 + c];
      o1[q] = lds[(rb + 8 + q) * 72 + c];
    }
    *(u16x8*)&dst[(long)(c0 + c) * Rd + r0 + rb] = o0;
    *(u16x8*)&dst[(long)(c0 + c) * Rd + r0 + rb + 8] = o1;
  }
}

// grid 960: [0,432) w_qkv tiles; [432,576) w_out tiles; [576,960) x cvt.
__global__ __launch_bounds__(256) void prep_k(const float* __restrict__ w_qkv,
                                              const float* __restrict__ w_out,
                                              const float* __restrict__ x,
                                              u16* __restrict__ wqkvT,
                                              u16* __restrict__ woutT,
                                              u16* __restrict__ xb) {
  __shared__ u16 lds[64 * 72];
  int bx = blockIdx.x;
  if (bx < 432) {
    int tr = bx / 36, tc = bx % 36;
    float sc = (tc < 12) ? 0.18033688011112042f : 1.0f;
    tp_tile(w_qkv, wqkvT, 2304, 768, tr * 64, tc * 64, sc, lds);
  } else if (bx < 576) {
    int t = bx - 432;
    tp_tile(w_out, woutT, 768, 768, (t / 12) * 64, (t % 12) * 64, 1.0f, lds);
  } else {
    // cvt x [8192][768] fp32 -> xb bf16: 384 blocks * 256 thr * 8 * 8 iters
    int base = ((bx - 576) * 256 + (int)threadIdx.x) * 8;
#pragma unroll
    for (int it = 0; it < 8; ++it, base += 786432) {
      f32x4 a = *(const f32x4*)&x[base];
      f32x4 b = *(const f32x4*)&x[base + 4];
      *(bf16x4*)&xb[base] = __builtin_convertvector(a, bf16x4);
      *(bf16x4*)&xb[base + 4] = __builtin_convertvector(b, bf16x4);
    }
  }
}

// ------- BT-GEMM core (all-bf16): C = A[M][K] @ BT[N][K]^T (+opt bias) -----
// R0-proven structure VERBATIM: single-buffer BK=32, 16 KB LDS,
// stage -> sync -> compute -> sync. FOUR structural edits regressed
// (R2 dbuf+setprio, R6 BK=64, R8 64x128 retile); only XCD swizzle won.
// DO NOT edit this core.
template <bool OF32>
__device__ __forceinline__ void gemm_core(const u16* __restrict__ A,
                                          const u16* __restrict__ BT,
                                          void* __restrict__ Cv,
                                          const float* __restrict__ bias,
                                          int N, int K, int br, int bc,
                                          u16* As, u16* Bs) {
  const int tid = threadIdx.x;
  const int lane = tid & 63, wave = tid >> 6;
  const int quad = lane >> 4, l16 = lane & 15;
  const int wm = (wave >> 1) * 64, wn = (wave & 1) * 64;

  f32x4 acc[4][4] = {};

  const int srow = wave * 32 + (lane >> 2);
  const int scol = ((lane & 3) ^ ((lane >> 3) & 3)) * 8;
  const u16* ag = A + (long)(br + srow) * K + scol;
  const u16* bg = BT + (long)(bc + srow) * K + scol;
  const int rd = (quad ^ ((l16 >> 1) & 3)) * 8;

  for (int k0 = 0; k0 < K; k0 += 32) {
    glds16(ag + k0, As + wave * 1024);
    glds16(ag + k0 + 16 * K, As + wave * 1024 + 512);
    glds16(bg + k0, Bs + wave * 1024);
    glds16(bg + k0 + 16 * K, Bs + wave * 1024 + 512);
    __syncthreads();
    bf16x8 af[4], bf[4];
#pragma unroll
    for (int i = 0; i < 4; ++i)
      af[i] = *(const bf16x8*)&As[(wm + i * 16 + l16) * 32 + rd];
#pragma unroll
    for (int j = 0; j < 4; ++j)
      bf[j] = *(const bf16x8*)&Bs[(wn + j * 16 + l16) * 32 + rd];
#pragma unroll
    for (int i = 0; i < 4; ++i)
#pragma unroll
      for (int j = 0; j < 4; ++j)
        acc[i][j] = __builtin_amdgcn_mfma_f32_16x16x32_bf16(af[i], bf[j],
                                                            acc[i][j], 0, 0, 0);
    __syncthreads();
  }

#pragma unroll
  for (int i = 0; i < 4; ++i)
#pragma unroll
    for (int j = 0; j < 4; ++j)
#pragma unroll
      for (int r = 0; r < 4; ++r) {
        int row = br + wm + i * 16 + quad * 4 + r;
        int col = bc + wn + j * 16 + l16;
        float v = acc[i][j][r];
        if (OF32) {
          ((float*)Cv)[(long)row * N + col] = v + bias[col];
        } else {
          ((__bf16*)Cv)[(long)row * N + col] = (__bf16)v;
        }
      }
}

// ---- fused: qk gemm (768 blocks) + vt gemm (384 blocks), all bf16 ----
// T1 XCD swizzle: 1152 % 8 == 0 -> bijective remap swz=(bid&7)*144+(bid>>3).
__global__ __launch_bounds__(256) void qkvt_k(const u16* __restrict__ xb,
                                              const u16* __restrict__ wqkvT,
                                              u16* __restrict__ qk,
                                              u16* __restrict__ vt) {
  __shared__ __align__(16) u16 As[128 * 32];
  __shared__ __align__(16) u16 Bs[128 * 32];
  int b0 = blockIdx.x;
  int bx = (b0 & 7) * 144 + (b0 >> 3);
  if (bx < 768) {
    gemm_core<false>(xb, wqkvT, qk, nullptr, 1536, 768, (bx / 12) * 128,
                     (bx % 12) * 128, As, Bs);
  } else {
    int i = bx - 768;  // 6 row-tiles x 64 col-tiles
    gemm_core<false>(wqkvT + 1536 * 768, xb, vt, nullptr, 8192, 768,
                     (i >> 6) * 128, (i & 63) * 128, As, Bs);
  }
}

// ---- gemm2: out[8192][768] = attnb @ woutT + bias (fp32 out) ----
// R7-proven config: 1D grid 384, 128x128 tiles, XCD swizzle.
__global__ __launch_bounds__(256) void gemm2_k(const u16* __restrict__ attnb,
                                               const u16* __restrict__ woutT,
                                               float* __restrict__ out,
                                               const float* __restrict__ bias) {
  __shared__ __align__(16) u16 As[128 * 32];
  __shared__ __align__(16) u16 Bs[128 * 32];
  int b0 = blockIdx.x;
  int swz = (b0 & 7) * 48 + (b0 >> 3);
  gemm_core<true>(attnb, woutT, out, bias, 768, 768, (swz / 6) * 128,
                  (swz % 6) * 128, As, Bs);
}

// ---------------- fused flash attention (XCD-swizzled grid) ----------------
// R2-proven 67us structure. QBLK=128, grid 768. Waves tile 2x2 over
// (q-half 64, s-half 32); K and V double-buffered; glds for t+1 issued at
// top of iter t; ONE vmcnt(0)+barrier per iter. Q direct global->reg.
// Q PRE-SCALED by log2(e)/8, so P = exp2(S).
// R10 edits: (1) l row-sums via VALU during exp (removes the 4 ones-MFMAs
// per iter = 11% of matrix-pipe work; epilogue does a one-time quad
// shfl_xor reduce -- same per-lane l distribution as the MFMA produced);
// (2) pipe_bar waits vmcnt only (lgkm redundant, see comment there).
// LDS: Ks[2][64*64] 16K + Vs[2][64*64] 16K + Ps[128*72] 18K = 51,200 B.
// DO NOT widen in-loop live ranges (R4: spill disaster).
__global__ __launch_bounds__(256, 3) void attn_k(const u16* __restrict__ qk,
                                                 const u16* __restrict__ vt,
                                                 u16* __restrict__ attnb) {
  const int LQ = 72;
  __shared__ __align__(16) u16 smem[16384 + 9216];
  u16* Ps = smem + 16384;

  const int tid = threadIdx.x;
  const int lane = tid & 63, wave = tid >> 6;
  const int quad = lane >> 4, l16 = lane & 15;
  const int qh = wave >> 1, sh = wave & 1;  // q-half 64 rows, s-half 32 rows
  const int bid = blockIdx.x;
  const int xcd = bid & 7, slot = bid >> 3;
  const int bh = xcd * 6 + (slot >> 4);
  const int qt = slot & 15;
  const int bloc = bh / 12, h = bh % 12;
  const long rowbase = (long)bloc * 2048;

  // glds staging: lane l -> tile row wave*16+(l>>3), logical chunk
  // ((l&7)^(l>>3)), phys chunk l&7; second glds covers rows +8.
  const int trow = lane >> 3;
  const int tcol = ((lane & 7) ^ trow) * 8;
  const u16* kg = qk + (rowbase + wave * 16 + trow) * 1536 + 768 + h * 64 + tcol;
  const u16* vg = vt + (long)(h * 64 + wave * 16 + trow) * 8192 + rowbase + tcol;

  // prologue: stage K0/V0 into buf0
  glds16(kg, smem + wave * 1024);
  glds16(kg + 8 * 1536, smem + wave * 1024 + 512);
  glds16(vg, smem + 8192 + wave * 1024);
  glds16(vg + 8 * 8192, smem + 8192 + wave * 1024 + 512);

  // Q fragments direct global->reg (one-time; L2-warm after qkvt_k)
  bf16x8 aq[2][4];
#pragma unroll
  for (int kk = 0; kk < 2; ++kk)
#pragma unroll
    for (int i = 0; i < 4; ++i)
      aq[kk][i] = *(const bf16x8*)&qk[(rowbase + qt * 128 + qh * 64 + i * 16 +
                                       l16) * 1536 + h * 64 + kk * 32 +
                                      quad * 8];

  const int sw = l16 & 7;
  f32x4 o[4][4] = {};               // partial O: 64 q x 64 d (this s-half)
  float lsum[4] = {0.f, 0.f, 0.f, 0.f};  // per-lane partial row-sums

  pipe_bar();  // K0/V0 staged, Q landed

#pragma unroll 2
  for (int t = 0; t < 32; ++t) {
    const int pb = t & 1;
    const u16* ksc = smem + pb * 4096;
    const u16* vsc = smem + 8192 + pb * 4096;
    if (t < 31) {
      u16* ksn = smem + (pb ^ 1) * 4096;
      u16* vsn = smem + 8192 + (pb ^ 1) * 4096;
      const long kvK = (long)(t + 1) * 64 * 1536;
      const long kvV = (long)(t + 1) * 64;
      glds16(kg + kvK, ksn + wave * 1024);
      glds16(kg + kvK + 8 * 1536, ksn + wave * 1024 + 512);
      glds16(vg + kvV, vsn + wave * 1024);
      glds16(vg + kvV + 8 * 8192, vsn + wave * 1024 + 512);
    }

    // S^T = K @ Q^T on this wave's s-half; one 16-row j-block at a time.
    // Output: col=l16=q_local, row=quad*4+r=s_local.
#pragma unroll
    for (int j = 0; j < 2; ++j) {
      bf16x8 bk0 = *(const bf16x8*)&ksc[(sh * 32 + j * 16 + l16) * 64 +
                                        (quad ^ sw) * 8];
      bf16x8 bk1 = *(const bf16x8*)&ksc[(sh * 32 + j * 16 + l16) * 64 +
                                        ((4 + quad) ^ sw) * 8];
      f32x4 sc[4] = {};
      __builtin_amdgcn_s_setprio(1);
#pragma unroll
      for (int i = 0; i < 4; ++i) {
        sc[i] = __builtin_amdgcn_mfma_f32_16x16x32_bf16(bk0, aq[0][i], sc[i],
                                                        0, 0, 0);
        sc[i] = __builtin_amdgcn_mfma_f32_16x16x32_bf16(bk1, aq[1][i], sc[i],
                                                        0, 0, 0);
      }
      __builtin_amdgcn_s_setprio(0);
      // P[q][s] = exp2(S); accumulate l in-register (replaces ones-MFMA)
#pragma unroll
      for (int i = 0; i < 4; ++i) {
        f32x4 p;
#pragma unroll
        for (int r = 0; r < 4; ++r)
          p[r] = __builtin_amdgcn_exp2f(sc[i][r]);
        lsum[i] += (p[0] + p[1]) + (p[2] + p[3]);
        *(bf16x4*)&Ps[(qh * 64 + i * 16 + l16) * LQ + sh * 32 + j * 16 +
                      quad * 4] = __builtin_convertvector(p, bf16x4);
      }
    }

    // O += P @ V over this wave's 32 s
    {
      bf16x8 bv[4];
#pragma unroll
      for (int n = 0; n < 4; ++n)
        bv[n] = *(const bf16x8*)&vsc[(n * 16 + l16) * 64 +
                                     ((sh * 4 + quad) ^ sw) * 8];
      __builtin_amdgcn_s_setprio(1);
#pragma unroll
      for (int i = 0; i < 4; ++i) {
        bf16x8 ap = *(const bf16x8*)&Ps[(qh * 64 + i * 16 + l16) * LQ +
                                        sh * 32 + quad * 8];
#pragma unroll
        for (int n = 0; n < 4; ++n)
          o[i][n] = __builtin_amdgcn_mfma_f32_16x16x32_bf16(ap, bv[n], o[i][n],
                                                            0, 0, 0);
      }
      __builtin_amdgcn_s_setprio(0);
    }

    pipe_bar();
  }

  // quad-reduce lsum: lane's partial covers s = {j*16 + quad*4 + r}; sum the
  // 4 quads (lane^16, lane^32) -> every lane holds l for q = qh*64+i*16+l16,
  // the same distribution the ones-MFMA produced.
#pragma unroll
  for (int i = 0; i < 4; ++i) {
    lsum[i] += __shfl_xor(lsum[i], 16, 64);
    lsum[i] += __shfl_xor(lsum[i], 32, 64);
  }

  // ---- cross-wave reduction: sh==1 stores partials, sh==0 combines ----
  float* Of = (float*)smem;            // [2 qh][64 q][64 d] f32 = 32768 B
  float* Lp = (float*)&smem[16384];    // [2 qh][64 q] f32 = 512 B
  if (sh == 1) {
#pragma unroll
    for (int i = 0; i < 4; ++i) {
#pragma unroll
      for (int n = 0; n < 4; ++n)
#pragma unroll
        for (int r = 0; r < 4; ++r)
          Of[(qh * 64 + i * 16 + quad * 4 + r) * 64 + n * 16 + l16] =
              o[i][n][r];
      if (quad == 0) Lp[qh * 64 + i * 16 + l16] = lsum[i];
    }
  }
  __syncthreads();
  if (sh == 0) {
#pragma unroll
    for (int i = 0; i < 4; ++i) {
      float lfull = lsum[i] + Lp[qh * 64 + i * 16 + l16];
      f32x4 inv;
#pragma unroll
      for (int r = 0; r < 4; ++r)
        inv[r] = 1.0f / __shfl(lfull, quad * 4 + r, 64);
#pragma unroll
      for (int n = 0; n < 4; ++n)
#pragma unroll
        for (int r = 0; r < 4; ++r) {
          int srow = qt * 128 + qh * 64 + i * 16 + quad * 4 + r;
          float v = o[i][n][r] +
                    Of[(qh * 64 + i * 16 + quad * 4 + r) * 64 + n * 16 + l16];
          ((__bf16*)attnb)[(rowbase + srow) * 768 + h * 64 + n * 16 + l16] =
              (__bf16)(v * inv[r]);
        }
    }
  }
}

extern "C" void kernel_launch(void* const* d_in, const int* in_sizes, int n_in,
                              void* d_out, int out_size, void* d_ws,
                              size_t ws_size, hipStream_t stream) {
  const float* x = (const float*)d_in[0];      // [4,2048,768] fp32
  const float* w_qkv = (const float*)d_in[1];  // [768,2304] fp32
  const float* w_out = (const float*)d_in[2];  // [768,768] fp32
  const float* b_out = (const float*)d_in[3];  // [768] fp32
  float* out = (float*)d_out;                  // [4,2048,768] fp32

  // ws (29,884,416 B, proven):
  //   wqkvT [2304][768] bf16   3,538,944   (Q rows pre-scaled by log2e/8)
  //   woutT [768][768]  bf16   1,179,648
  //   vt    [768][8192] bf16  12,582,912
  //   xb/attnb (aliased)      12,582,912
  // qk [8192][1536] bf16 (25,165,824 B) lives in d_out until gemm2 overwrites.
  char* ws = (char*)d_ws;
  u16* wqkvT = (u16*)(ws);
  u16* woutT = (u16*)(ws + 3538944);
  u16* vt = (u16*)(ws + 4718592);
  u16* xb = (u16*)(ws + 17301504);
  u16* attnb = xb;
  u16* qkb = (u16*)d_out;

  prep_k<<<960, 256, 0, stream>>>(w_qkv, w_out, x, wqkvT, woutT, xb);
  qkvt_k<<<1152, 256, 0, stream>>>(xb, wqkvT, qkb, vt);
  attn_k<<<768, 256, 0, stream>>>(qkb, vt, attnb);
  gemm2_k<<<384, 256, 0, stream>>>(attnb, woutT, out, b_out);
}

// Round 12
// 203.045 us; speedup vs baseline: 1.3403x; 1.3403x over previous
//
#include <hip/hip_runtime.h>
#include <stdint.h>

typedef unsigned short u16;
typedef __attribute__((ext_vector_type(8))) __bf16 bf16x8;
typedef __attribute__((ext_vector_type(4))) __bf16 bf16x4;
typedef __attribute__((ext_vector_type(8))) unsigned short u16x8;
typedef __attribute__((ext_vector_type(4))) float f32x4;

// async global->LDS, 16B/lane; LDS dest = wave-uniform base + lane*16.
__device__ __forceinline__ void glds16(const u16* g, u16* l) {
  auto* gp = reinterpret_cast<const __attribute__((address_space(1))) unsigned*>(
      reinterpret_cast<uintptr_t>(g));
  auto* lp = reinterpret_cast<__attribute__((address_space(3))) unsigned*>(
      reinterpret_cast<uintptr_t>(l));
  __builtin_amdgcn_global_load_lds(gp, lp, 16, 0, 0);
}

// drain own vmem+lds, then raw barrier. (R11 showed the vmcnt-only variant
// participates in a spill regression -- keep the full drain.)
__device__ __forceinline__ void pipe_bar() {
  asm volatile("s_waitcnt vmcnt(0) lgkmcnt(0)" ::: "memory");
  __builtin_amdgcn_s_barrier();
  asm volatile("" ::: "memory");
}

// ---------------- prep: weight transposes + x cvt (fp32 -> bf16) ----------
// scale folded in BEFORE the bf16 round (pre-scales Q by log2e/8).
__device__ __forceinline__ void tp_tile(const float* __restrict__ src,
                                        u16* __restrict__ dst, int C, int Rd,
                                        int r0, int c0, float scale, u16* lds) {
  const int tid = threadIdx.x;
  {
    int r = tid >> 2, cb = (tid & 3) * 16;
#pragma unroll
    for (int k = 0; k < 4; ++k) {
      f32x4 v = *(const f32x4*)&src[(long)(r0 + r) * C + c0 + cb + k * 4];
      v = v * scale;
      *(bf16x4*)&lds[r * 72 + cb + k * 4] = __builtin_convertvector(v, bf16x4);
    }
  }
  __syncthreads();
  {
    int c = tid >> 2, rb = (tid & 3) * 16;
    u16x8 o0, o1;
#pragma unroll
    for (int q = 0; q < 8; ++q) {
      o0[q] = lds[(rb + q) * 72 + c];
      o1[q] = lds[(rb + 8 + q) * 72 + c];
    }
    *(u16x8*)&dst[(long)(c0 + c) * Rd + r0 + rb] = o0;
    *(u16x8*)&dst[(long)(c0 + c) * Rd + r0 + rb + 8] = o1;
  }
}

// grid 768: [0,432) w_qkv tiles; [432,576) w_out tiles; [576,768) x cvt.
__global__ __launch_bounds__(256) void prep_k(const float* __restrict__ w_qkv,
                                              const float* __restrict__ w_out,
                                              const float* __restrict__ x,
                                              u16* __restrict__ wqkvT,
                                              u16* __restrict__ woutT,
                                              u16* __restrict__ xb) {
  __shared__ u16 lds[64 * 72];
  int bx = blockIdx.x;
  if (bx < 432) {
    int tr = bx / 36, tc = bx % 36;
    float sc = (tc < 12) ? 0.18033688011112042f : 1.0f;
    tp_tile(w_qkv, wqkvT, 2304, 768, tr * 64, tc * 64, sc, lds);
  } else if (bx < 576) {
    int t = bx - 432;
    tp_tile(w_out, woutT, 768, 768, (t / 12) * 64, (t % 12) * 64, 1.0f, lds);
  } else {
    int base = ((bx - 576) * 256 + (int)threadIdx.x) * 8;
#pragma unroll
    for (int it = 0; it < 16; ++it, base += 393216) {
      f32x4 a = *(const f32x4*)&x[base];
      f32x4 b = *(const f32x4*)&x[base + 4];
      *(bf16x4*)&xb[base] = __builtin_convertvector(a, bf16x4);
      *(bf16x4*)&xb[base + 4] = __builtin_convertvector(b, bf16x4);
    }
  }
}

// ------- BT-GEMM core (all-bf16): C = A[M][K] @ BT[N][K]^T (+opt bias) -----
// R0-proven structure VERBATIM: single-buffer BK=32, 16 KB LDS,
// stage -> sync -> compute -> sync. FOUR structural edits regressed
// (R2 dbuf+setprio, R6 BK=64, R8 64x128 retile); only XCD swizzle won.
// DO NOT edit this core.
template <bool OF32>
__device__ __forceinline__ void gemm_core(const u16* __restrict__ A,
                                          const u16* __restrict__ BT,
                                          void* __restrict__ Cv,
                                          const float* __restrict__ bias,
                                          int N, int K, int br, int bc,
                                          u16* As, u16* Bs) {
  const int tid = threadIdx.x;
  const int lane = tid & 63, wave = tid >> 6;
  const int quad = lane >> 4, l16 = lane & 15;
  const int wm = (wave >> 1) * 64, wn = (wave & 1) * 64;

  f32x4 acc[4][4] = {};

  const int srow = wave * 32 + (lane >> 2);
  const int scol = ((lane & 3) ^ ((lane >> 3) & 3)) * 8;
  const u16* ag = A + (long)(br + srow) * K + scol;
  const u16* bg = BT + (long)(bc + srow) * K + scol;
  const int rd = (quad ^ ((l16 >> 1) & 3)) * 8;

  for (int k0 = 0; k0 < K; k0 += 32) {
    glds16(ag + k0, As + wave * 1024);
    glds16(ag + k0 + 16 * K, As + wave * 1024 + 512);
    glds16(bg + k0, Bs + wave * 1024);
    glds16(bg + k0 + 16 * K, Bs + wave * 1024 + 512);
    __syncthreads();
    bf16x8 af[4], bf[4];
#pragma unroll
    for (int i = 0; i < 4; ++i)
      af[i] = *(const bf16x8*)&As[(wm + i * 16 + l16) * 32 + rd];
#pragma unroll
    for (int j = 0; j < 4; ++j)
      bf[j] = *(const bf16x8*)&Bs[(wn + j * 16 + l16) * 32 + rd];
#pragma unroll
    for (int i = 0; i < 4; ++i)
#pragma unroll
      for (int j = 0; j < 4; ++j)
        acc[i][j] = __builtin_amdgcn_mfma_f32_16x16x32_bf16(af[i], bf[j],
                                                            acc[i][j], 0, 0, 0);
    __syncthreads();
  }

#pragma unroll
  for (int i = 0; i < 4; ++i)
#pragma unroll
    for (int j = 0; j < 4; ++j)
#pragma unroll
      for (int r = 0; r < 4; ++r) {
        int row = br + wm + i * 16 + quad * 4 + r;
        int col = bc + wn + j * 16 + l16;
        float v = acc[i][j][r];
        if (OF32) {
          ((float*)Cv)[(long)row * N + col] = v + bias[col];
        } else {
          ((__bf16*)Cv)[(long)row * N + col] = (__bf16)v;
        }
      }
}

// ---- fused: qk gemm (768 blocks) + vt gemm (384 blocks), all bf16 ----
// T1 XCD swizzle: 1152 % 8 == 0 -> bijective remap swz=(bid&7)*144+(bid>>3).
__global__ __launch_bounds__(256) void qkvt_k(const u16* __restrict__ xb,
                                              const u16* __restrict__ wqkvT,
                                              u16* __restrict__ qk,
                                              u16* __restrict__ vt) {
  __shared__ __align__(16) u16 As[128 * 32];
  __shared__ __align__(16) u16 Bs[128 * 32];
  int b0 = blockIdx.x;
  int bx = (b0 & 7) * 144 + (b0 >> 3);
  if (bx < 768) {
    gemm_core<false>(xb, wqkvT, qk, nullptr, 1536, 768, (bx / 12) * 128,
                     (bx % 12) * 128, As, Bs);
  } else {
    int i = bx - 768;  // 6 row-tiles x 64 col-tiles
    gemm_core<false>(wqkvT + 1536 * 768, xb, vt, nullptr, 8192, 768,
                     (i >> 6) * 128, (i & 63) * 128, As, Bs);
  }
}

// ---- gemm2: out[8192][768] = attnb @ woutT + bias (fp32 out) ----
// R7-proven config: 1D grid 384, 128x128 tiles, XCD swizzle
// swz=(bid&7)*48+(bid>>3).
__global__ __launch_bounds__(256) void gemm2_k(const u16* __restrict__ attnb,
                                               const u16* __restrict__ woutT,
                                               float* __restrict__ out,
                                               const float* __restrict__ bias) {
  __shared__ __align__(16) u16 As[128 * 32];
  __shared__ __align__(16) u16 Bs[128 * 32];
  int b0 = blockIdx.x;
  int swz = (b0 & 7) * 48 + (b0 >> 3);
  gemm_core<true>(attnb, woutT, out, bias, 768, 768, (swz / 6) * 128,
                  (swz % 6) * 128, As, Bs);
}

// ---------------- fused flash attention (XCD-swizzled grid) ----------------
// R2-proven 67-68us structure (R5/R7/R9-verified) -- FINAL.
// QBLK=128, grid 768. xcd=bid&7, slot=bid>>3, bh=xcd*6+(slot>>4), qt=slot&15.
// Waves tile 2x2 over (q-half 64, s-half 32); cross-wave O reduce epilogue.
// K and V BOTH double-buffered; glds for t+1 issued at top of iter t; ONE
// vmcnt(0)+barrier at end of iter. Per-j QK (sc[4] live at a time) -> exp ->
// P store; PV after. setprio around MFMA clusters only. Q direct
// global->reg in prologue. Q PRE-SCALED by log2(e)/8, so P = exp2(S).
// LDS: Ks[2][64*64] 16K + Vs[2][64*64] 16K + Ps[128*72] 18K = 51,200 B.
// Register ceiling is binding: R4 (sc[2][4]+bv hoist) AND R11 (VALU lsum +
// vmcnt-only barrier) both spilled to scratch (WRITE_SIZE 12MB -> 200-320MB,
// 2x regression) with unchanged reported VGPR. DO NOT reshape in-loop live
// ranges, including the ones-MFMA l accumulator.
__global__ __launch_bounds__(256, 3) void attn_k(const u16* __restrict__ qk,
                                                 const u16* __restrict__ vt,
                                                 u16* __restrict__ attnb) {
  const int LQ = 72;
  __shared__ __align__(16) u16 smem[16384 + 9216];
  u16* Ps = smem + 16384;

  const int tid = threadIdx.x;
  const int lane = tid & 63, wave = tid >> 6;
  const int quad = lane >> 4, l16 = lane & 15;
  const int qh = wave >> 1, sh = wave & 1;  // q-half 64 rows, s-half 32 rows
  const int bid = blockIdx.x;
  const int xcd = bid & 7, slot = bid >> 3;
  const int bh = xcd * 6 + (slot >> 4);
  const int qt = slot & 15;
  const int bloc = bh / 12, h = bh % 12;
  const long rowbase = (long)bloc * 2048;

  // glds staging: lane l -> tile row wave*16+(l>>3), logical chunk
  // ((l&7)^(l>>3)), phys chunk l&7; second glds covers rows +8.
  const int trow = lane >> 3;
  const int tcol = ((lane & 7) ^ trow) * 8;
  const u16* kg = qk + (rowbase + wave * 16 + trow) * 1536 + 768 + h * 64 + tcol;
  const u16* vg = vt + (long)(h * 64 + wave * 16 + trow) * 8192 + rowbase + tcol;

  // prologue: stage K0/V0 into buf0
  glds16(kg, smem + wave * 1024);
  glds16(kg + 8 * 1536, smem + wave * 1024 + 512);
  glds16(vg, smem + 8192 + wave * 1024);
  glds16(vg + 8 * 8192, smem + 8192 + wave * 1024 + 512);

  // Q fragments direct global->reg (one-time; L2-warm after qkvt_k)
  bf16x8 aq[2][4];
#pragma unroll
  for (int kk = 0; kk < 2; ++kk)
#pragma unroll
    for (int i = 0; i < 4; ++i)
      aq[kk][i] = *(const bf16x8*)&qk[(rowbase + qt * 128 + qh * 64 + i * 16 +
                                       l16) * 1536 + h * 64 + kk * 32 +
                                      quad * 8];

  bf16x8 ones;
#pragma unroll
  for (int q = 0; q < 8; ++q) ones[q] = (__bf16)1.0f;

  const int sw = l16 & 7;
  f32x4 o[4][4] = {};    // partial O: 64 q x 64 d over this wave's s-half
  f32x4 l_acc[4] = {};   // partial row-sums

  pipe_bar();  // K0/V0 staged, Q landed

#pragma unroll 2
  for (int t = 0; t < 32; ++t) {
    const int pb = t & 1;
    const u16* ksc = smem + pb * 4096;
    const u16* vsc = smem + 8192 + pb * 4096;
    if (t < 31) {
      u16* ksn = smem + (pb ^ 1) * 4096;
      u16* vsn = smem + 8192 + (pb ^ 1) * 4096;
      const long kvK = (long)(t + 1) * 64 * 1536;
      const long kvV = (long)(t + 1) * 64;
      glds16(kg + kvK, ksn + wave * 1024);
      glds16(kg + kvK + 8 * 1536, ksn + wave * 1024 + 512);
      glds16(vg + kvV, vsn + wave * 1024);
      glds16(vg + kvV + 8 * 8192, vsn + wave * 1024 + 512);
    }

    // S^T = K @ Q^T on this wave's s-half; one 16-row j-block at a time.
    // Output: col=l16=q_local, row=quad*4+r=s_local.
#pragma unroll
    for (int j = 0; j < 2; ++j) {
      bf16x8 bk0 = *(const bf16x8*)&ksc[(sh * 32 + j * 16 + l16) * 64 +
                                        (quad ^ sw) * 8];
      bf16x8 bk1 = *(const bf16x8*)&ksc[(sh * 32 + j * 16 + l16) * 64 +
                                        ((4 + quad) ^ sw) * 8];
      f32x4 sc[4] = {};
      __builtin_amdgcn_s_setprio(1);
#pragma unroll
      for (int i = 0; i < 4; ++i) {
        sc[i] = __builtin_amdgcn_mfma_f32_16x16x32_bf16(bk0, aq[0][i], sc[i],
                                                        0, 0, 0);
        sc[i] = __builtin_amdgcn_mfma_f32_16x16x32_bf16(bk1, aq[1][i], sc[i],
                                                        0, 0, 0);
      }
      __builtin_amdgcn_s_setprio(0);
      // P[q][s] = exp2(S) (scale pre-folded into Q); wave-private chunk
#pragma unroll
      for (int i = 0; i < 4; ++i) {
        f32x4 p;
#pragma unroll
        for (int r = 0; r < 4; ++r)
          p[r] = __builtin_amdgcn_exp2f(sc[i][r]);
        *(bf16x4*)&Ps[(qh * 64 + i * 16 + l16) * LQ + sh * 32 + j * 16 +
                      quad * 4] = __builtin_convertvector(p, bf16x4);
      }
    }

    // O += P @ V over this wave's 32 s; l += ones @ P
    {
      bf16x8 bv[4];
#pragma unroll
      for (int n = 0; n < 4; ++n)
        bv[n] = *(const bf16x8*)&vsc[(n * 16 + l16) * 64 +
                                     ((sh * 4 + quad) ^ sw) * 8];
      __builtin_amdgcn_s_setprio(1);
#pragma unroll
      for (int i = 0; i < 4; ++i) {
        bf16x8 ap = *(const bf16x8*)&Ps[(qh * 64 + i * 16 + l16) * LQ +
                                        sh * 32 + quad * 8];
        l_acc[i] = __builtin_amdgcn_mfma_f32_16x16x32_bf16(ones, ap, l_acc[i],
                                                           0, 0, 0);
#pragma unroll
        for (int n = 0; n < 4; ++n)
          o[i][n] = __builtin_amdgcn_mfma_f32_16x16x32_bf16(ap, bv[n], o[i][n],
                                                            0, 0, 0);
      }
      __builtin_amdgcn_s_setprio(0);
    }

    pipe_bar();
  }

  // ---- cross-wave reduction: sh==1 stores partials, sh==0 combines ----
  float* Of = (float*)smem;            // [2 qh][64 q][64 d] f32 = 32768 B
  float* Lp = (float*)&smem[16384];    // [2 qh][64 q] f32 = 512 B
  if (sh == 1) {
#pragma unroll
    for (int i = 0; i < 4; ++i) {
#pragma unroll
      for (int n = 0; n < 4; ++n)
#pragma unroll
        for (int r = 0; r < 4; ++r)
          Of[(qh * 64 + i * 16 + quad * 4 + r) * 64 + n * 16 + l16] =
              o[i][n][r];
      if (quad == 0) Lp[qh * 64 + i * 16 + l16] = l_acc[i][0];
    }
  }
  __syncthreads();
  if (sh == 0) {
#pragma unroll
    for (int i = 0; i < 4; ++i) {
      float lsum = l_acc[i][0] + Lp[qh * 64 + i * 16 + l16];
      f32x4 inv;
#pragma unroll
      for (int r = 0; r < 4; ++r)
        inv[r] = 1.0f / __shfl(lsum, quad * 4 + r, 64);
#pragma unroll
      for (int n = 0; n < 4; ++n)
#pragma unroll
        for (int r = 0; r < 4; ++r) {
          int srow = qt * 128 + qh * 64 + i * 16 + quad * 4 + r;
          float v = o[i][n][r] +
                    Of[(qh * 64 + i * 16 + quad * 4 + r) * 64 + n * 16 + l16];
          ((__bf16*)attnb)[(rowbase + srow) * 768 + h * 64 + n * 16 + l16] =
              (__bf16)(v * inv[r]);
        }
    }
  }
}

extern "C" void kernel_launch(void* const* d_in, const int* in_sizes, int n_in,
                              void* d_out, int out_size, void* d_ws,
                              size_t ws_size, hipStream_t stream) {
  const float* x = (const float*)d_in[0];      // [4,2048,768] fp32
  const float* w_qkv = (const float*)d_in[1];  // [768,2304] fp32
  const float* w_out = (const float*)d_in[2];  // [768,768] fp32
  const float* b_out = (const float*)d_in[3];  // [768] fp32
  float* out = (float*)d_out;                  // [4,2048,768] fp32

  // ws (29,884,416 B, proven):
  //   wqkvT [2304][768] bf16   3,538,944   (Q rows pre-scaled by log2e/8)
  //   woutT [768][768]  bf16   1,179,648
  //   vt    [768][8192] bf16  12,582,912
  //   xb/attnb (aliased)      12,582,912
  // qk [8192][1536] bf16 (25,165,824 B) lives in d_out until gemm2 overwrites.
  char* ws = (char*)d_ws;
  u16* wqkvT = (u16*)(ws);
  u16* woutT = (u16*)(ws + 3538944);
  u16* vt = (u16*)(ws + 4718592);
  u16* xb = (u16*)(ws + 17301504);
  u16* attnb = xb;
  u16* qkb = (u16*)d_out;

  prep_k<<<768, 256, 0, stream>>>(w_qkv, w_out, x, wqkvT, woutT, xb);
  qkvt_k<<<1152, 256, 0, stream>>>(xb, wqkvT, qkb, vt);
  attn_k<<<768, 256, 0, stream>>>(qkb, vt, attnb);
  gemm2_k<<<384, 256, 0, stream>>>(attnb, woutT, out, b_out);
}